// Round 1
// baseline (9175.314 us; speedup 1.0000x reference)
//
#include <hip/hip_runtime.h>

#define DEV __device__ __forceinline__

typedef __attribute__((ext_vector_type(8))) short short8;
typedef __attribute__((ext_vector_type(8))) __bf16 bf8_t;
typedef __attribute__((ext_vector_type(2))) __bf16 bf2_t;
typedef __attribute__((ext_vector_type(4))) float f32x4;
typedef __attribute__((ext_vector_type(4))) unsigned int u32x4;
typedef __attribute__((ext_vector_type(2))) unsigned int u32x2;

// native gfx950 cvt (v_cvt_pk_bf16_f32), RNE — numerically identical to the
// old manual round-to-nearest-even sequence but ~3x fewer VALU ops.
DEV unsigned short f2bf(float f){
  return __builtin_bit_cast(unsigned short, (__bf16)f);
}
DEV unsigned pk2(float a, float b){
  bf2_t t; t[0] = (__bf16)a; t[1] = (__bf16)b;
  return __builtin_bit_cast(unsigned, t);
}
DEV void g2l16(const void* g, const void* l){
  __builtin_amdgcn_global_load_lds((const __attribute__((address_space(1))) void*)g,
                                   (__attribute__((address_space(3))) void*)l, 16, 0, 0);
}
DEV f32x4 mfma16(short8 a, short8 b, f32x4 c){
  return __builtin_amdgcn_mfma_f32_16x16x32_bf16(
      __builtin_bit_cast(bf8_t, a), __builtin_bit_cast(bf8_t, b), c, 0, 0, 0);
}

// ---------------- fp32 -> bf16 convert ----------------
__global__ __launch_bounds__(256) void k_cvt(const float* __restrict__ src,
                                             unsigned short* __restrict__ dst, int n4){
  int stride = gridDim.x * 256;
  for (int i = blockIdx.x * 256 + threadIdx.x; i < n4; i += stride){
    float4 v = ((const float4*)src)[i];
    u32x2 o; o.x = pk2(v.x, v.y); o.y = pk2(v.z, v.w);
    ((u32x2*)dst)[i] = o;
  }
}

// ---------------- QKV GEMM: C = x @ W^T + b, fused RoPE, writes Q(bf16 ws) / K,V(fp32 cache) ----
// 128x128 tile, BK=64, 4 waves each computing a 64x64 quadrant of 16x16x32 MFMAs.
template<int USE_WB>
__global__ __launch_bounds__(256, 2) void k_gemm(
    const unsigned short* __restrict__ xb,
    const unsigned short* __restrict__ wb,
    const float* __restrict__ wq, const float* __restrict__ wk, const float* __restrict__ wv,
    const float* __restrict__ bq, const float* __restrict__ bk, const float* __restrict__ bv,
    const float* __restrict__ fcos, const float* __restrict__ fsin,
    const int* __restrict__ spp,
    unsigned short* __restrict__ Qb,
    float* __restrict__ ck, float* __restrict__ cv)
{
  __shared__ __align__(16) short As[128*64];
  __shared__ __align__(16) short Bs[128*64];
  const int tid  = threadIdx.x;
  const int lane = tid & 63, w = tid >> 6;
  const int l15  = lane & 15, quad = lane >> 4;
  const int z  = blockIdx.z;
  const int tn = blockIdx.x >> 4, tm = blockIdx.x & 15;
  const int m0 = tm * 128, n0 = tn * 128;
  const int sp = *spp;
  const float* Wz = (z == 0) ? wq : (z == 1) ? wk : wv;
  const float* Bz = (z == 0) ? bq : (z == 1) ? bk : bv;
  const unsigned short* wbz = wb + (size_t)z * 4096 * 4096;
  const int wm = w >> 1, wn = w & 1;

  f32x4 acc[4][4];
  #pragma unroll
  for (int i = 0; i < 4; i++)
    #pragma unroll
    for (int j = 0; j < 4; j++) acc[i][j] = (f32x4)0.f;

  for (int kt = 0; kt < 64; ++kt){
    const int k0 = kt * 64;
    #pragma unroll
    for (int i = 0; i < 4; i++){
      int ci = (w*4 + i)*64 + lane;
      int row = ci >> 3, cc = (ci & 7) ^ (row & 7);
      g2l16(xb + (size_t)(m0 + row)*4096 + k0 + cc*8, (char*)As + (w*4 + i)*1024);
    }
    if (USE_WB){
      #pragma unroll
      for (int i = 0; i < 4; i++){
        int ci = (w*4 + i)*64 + lane;
        int row = ci >> 3, cc = (ci & 7) ^ (row & 7);
        g2l16(wbz + (size_t)(n0 + row)*4096 + k0 + cc*8, (char*)Bs + (w*4 + i)*1024);
      }
    } else {
      #pragma unroll
      for (int j = 0; j < 4; j++){
        int ci = j*256 + tid;
        int row = ci >> 3, cc = (ci & 7) ^ (row & 7);
        const float4* gp = (const float4*)(Wz + (size_t)(n0 + row)*4096 + k0 + cc*8);
        float4 f0 = gp[0], f1 = gp[1];
        u32x4 p; p.x = pk2(f0.x, f0.y); p.y = pk2(f0.z, f0.w);
                 p.z = pk2(f1.x, f1.y); p.w = pk2(f1.z, f1.w);
        *(u32x4*)&Bs[ci*8] = p;
      }
    }
    __syncthreads();
    #pragma unroll
    for (int ks = 0; ks < 2; ++ks){
      short8 af[4], bf[4];
      #pragma unroll
      for (int mi = 0; mi < 4; mi++){
        int row = wm*64 + mi*16 + l15;
        int cc = (ks*4 + quad) ^ (row & 7);
        af[mi] = *(const short8*)&As[row*64 + cc*8];
      }
      #pragma unroll
      for (int ni = 0; ni < 4; ni++){
        int row = wn*64 + ni*16 + l15;
        int cc = (ks*4 + quad) ^ (row & 7);
        bf[ni] = *(const short8*)&Bs[row*64 + cc*8];
      }
      #pragma unroll
      for (int mi = 0; mi < 4; mi++)
        #pragma unroll
        for (int ni = 0; ni < 4; ni++)
          acc[mi][ni] = mfma16(af[mi], bf[ni], acc[mi][ni]);
    }
    __syncthreads();
  }

  // epilogue: bias, RoPE (Q,K), 1/sqrt(128) folded into Q, scatter stores
  #pragma unroll
  for (int ni = 0; ni < 4; ni++){
    const int col = n0 + wn*64 + ni*16 + l15;
    const float bias_v = Bz[col];
    #pragma unroll
    for (int mi = 0; mi < 4; mi++){
      #pragma unroll
      for (int r = 0; r < 4; r++){
        int rowl = wm*64 + mi*16 + quad*4 + r;
        int m = m0 + rowl;
        int s = m & 511, bb = m >> 9;
        float v = acc[mi][ni][r] + bias_v;
        if (z < 2){
          int fi = (col & 127) >> 1;
          float c = fcos[s*64 + fi], sn = fsin[s*64 + fi];
          float vo = __shfl_xor(v, 1);
          v = (lane & 1) ? (vo*sn + v*c) : (v*c - vo*sn);
        }
        if (z == 0){
          Qb[(size_t)m*4096 + col] = f2bf(v * 0.08838834764831843f);
        } else {
          float* dst = (z == 1) ? ck : cv;
          dst[(((size_t)bb*4096 + sp + s)*32 + (col >> 7))*128 + (col & 127)] = v;
        }
      }
    }
  }
}

// ---------------- Flash attention over full KV cache ----------------
// v2: 512-thread blocks (8 waves x 16 q-rows), Q direct-to-reg (no Q LDS),
// double-buffered K/V tiles with register-staged prefetch (1 barrier/tile),
// native cvt_pk conversions, XCD-chunked block swizzle, setprio on MFMA.
// LDS: Ks 2x16KB + Vts 2x16KB + Ps 16KB = 80KB -> 2 blocks (16 waves)/CU.
__global__ __launch_bounds__(512, 4) void k_attn(
    const unsigned short* __restrict__ Qb,
    const float* __restrict__ ck, const float* __restrict__ cv,
    const int* __restrict__ spp,
    float* __restrict__ out)
{
  __shared__ __align__(16) short Ks [2][64*128];  // [key][128d], chunk-swizzled ^(key&15)
  __shared__ __align__(16) short Vts[2][128*64];  // [d][64key],  chunk-swizzled ^(d&7)
  __shared__ __align__(16) short Ps [128*64];     // P [row][64],  chunk-swizzled ^(row&7)

  const int tid  = threadIdx.x;
  const int lane = tid & 63, w = tid >> 6;        // 8 waves, wave w owns q-rows w*16..w*16+15
  const int l15  = lane & 15, quad = lane >> 4;
  // XCD-chunked swizzle: 8 XCDs x 64 consecutive logical blocks -> the 4 q-tiles
  // of each (b,h) are co-resident on one XCD and share KV via its L2.
  const int bid  = blockIdx.x;
  const int orig = (bid & 7) * 64 + (bid >> 3);
  const int bh = orig >> 2, qt = orig & 3;
  const int b = bh >> 5, h = bh & 31;
  const int sp = *spp;
  const int nkt = (sp + 512) >> 6;
  const float LOG2E = 1.4426950408889634f;

  // staging geometry (512 threads)
  const int kkey = tid >> 3;          // 0..63   key row
  const int kdc  = (tid & 7) * 16;    // d chunk start (16 floats)
  const int vd   = tid & 127;         // 0..127  d row of V^T
  const int vg   = tid >> 7;          // 0..3    key group (16 keys)
  const size_t bofs = (size_t)b * 4096 * 4096;
  const float* kp = ck + bofs + h*128;
  const float* vp = cv + bofs + h*128;

  // Q fragments straight from global (16B contiguous per fragment)
  const int qrow = b*512 + qt*128 + w*16 + l15;
  short8 qf[4];
  #pragma unroll
  for (int ks = 0; ks < 4; ks++)
    qf[ks] = *(const short8*)&Qb[(size_t)qrow*4096 + h*128 + (ks*4 + quad)*8];

  f32x4 oacc[8];
  #pragma unroll
  for (int ni = 0; ni < 8; ni++) oacc[ni] = (f32x4)0.f;
  float Mx[4], Ln[4];
  #pragma unroll
  for (int r = 0; r < 4; r++){ Mx[r] = -1e30f; Ln[r] = 0.f; }

  float4 k0, k1, k2, k3; float vf[16];

#define KV_LOAD(KB) {                                                          \
    const float4* kg_ = (const float4*)(kp + (size_t)((KB)*64 + kkey)*4096 + kdc); \
    k0 = kg_[0]; k1 = kg_[1]; k2 = kg_[2]; k3 = kg_[3];                        \
    const float* vg_ = vp + (size_t)((KB)*64 + vg*16)*4096 + vd;               \
    _Pragma("unroll")                                                          \
    for (int j = 0; j < 16; j++) vf[j] = vg_[(size_t)j*4096]; }

#define KV_WRITE(BUF) {                                                        \
    u32x4 p_; const int c0_ = (tid & 7) * 2;                                   \
    p_.x = pk2(k0.x,k0.y); p_.y = pk2(k0.z,k0.w);                              \
    p_.z = pk2(k1.x,k1.y); p_.w = pk2(k1.z,k1.w);                              \
    *(u32x4*)&Ks[BUF][kkey*128 + ((c0_  ) ^ (kkey & 15))*8] = p_;              \
    p_.x = pk2(k2.x,k2.y); p_.y = pk2(k2.z,k2.w);                              \
    p_.z = pk2(k3.x,k3.y); p_.w = pk2(k3.z,k3.w);                              \
    *(u32x4*)&Ks[BUF][kkey*128 + ((c0_+1) ^ (kkey & 15))*8] = p_;              \
    p_.x = pk2(vf[0],vf[1]);  p_.y = pk2(vf[2],vf[3]);                         \
    p_.z = pk2(vf[4],vf[5]);  p_.w = pk2(vf[6],vf[7]);                         \
    *(u32x4*)&Vts[BUF][vd*64 + ((vg*2  ) ^ (vd & 7))*8] = p_;                  \
    p_.x = pk2(vf[8],vf[9]);  p_.y = pk2(vf[10],vf[11]);                       \
    p_.z = pk2(vf[12],vf[13]); p_.w = pk2(vf[14],vf[15]);                      \
    *(u32x4*)&Vts[BUF][vd*64 + ((vg*2+1) ^ (vd & 7))*8] = p_; }

  // prologue: stage tile 0 into buffer 0
  KV_LOAD(0);
  KV_WRITE(0);
  __syncthreads();

  int cur = 0;
  for (int kb = 0; kb < nkt; ++kb){
    const bool more = (kb + 1 < nkt);
    if (more) KV_LOAD(kb + 1);   // loads in flight under QK^T + softmax

    // S = Q K^T (scores pre-scaled via Q)
    f32x4 sa[4];
    #pragma unroll
    for (int ni = 0; ni < 4; ni++) sa[ni] = (f32x4)0.f;
    #pragma unroll
    for (int ks = 0; ks < 4; ks++){
      short8 bfr[4];
      #pragma unroll
      for (int ni = 0; ni < 4; ni++){
        int key = ni*16 + l15;
        int cc = (ks*4 + quad) ^ (key & 15);
        bfr[ni] = *(const short8*)&Ks[cur][key*128 + cc*8];
      }
      __builtin_amdgcn_s_setprio(1);
      #pragma unroll
      for (int ni = 0; ni < 4; ni++)
        sa[ni] = mfma16(qf[ks], bfr[ni], sa[ni]);
      __builtin_amdgcn_s_setprio(0);
    }

    // online softmax (reduce across the 16-lane col group)
    float rmax[4], al[4], rsum[4];
    #pragma unroll
    for (int r = 0; r < 4; r++)
      rmax[r] = fmaxf(fmaxf(sa[0][r], sa[1][r]), fmaxf(sa[2][r], sa[3][r]));
    #pragma unroll
    for (int off = 1; off <= 8; off <<= 1)
      #pragma unroll
      for (int r = 0; r < 4; r++)
        rmax[r] = fmaxf(rmax[r], __shfl_xor(rmax[r], off));
    #pragma unroll
    for (int r = 0; r < 4; r++){
      float Mn = fmaxf(Mx[r], rmax[r]);
      al[r] = exp2f((Mx[r] - Mn) * LOG2E);
      Mx[r] = Mn; rsum[r] = 0.f;
    }
    #pragma unroll
    for (int ni = 0; ni < 4; ni++){
      int colb = ni*16 + l15;
      #pragma unroll
      for (int r = 0; r < 4; r++){
        float pv = exp2f((sa[ni][r] - Mx[r]) * LOG2E);
        rsum[r] += pv;
        int row = w*16 + quad*4 + r;
        int cc = (colb >> 3) ^ (row & 7);
        Ps[row*64 + cc*8 + (colb & 7)] = (short)f2bf(pv);
      }
    }
    #pragma unroll
    for (int off = 1; off <= 8; off <<= 1)
      #pragma unroll
      for (int r = 0; r < 4; r++)
        rsum[r] += __shfl_xor(rsum[r], off);
    #pragma unroll
    for (int r = 0; r < 4; r++) Ln[r] = Ln[r]*al[r] + rsum[r];
    #pragma unroll
    for (int ni = 0; ni < 8; ni++)
      #pragma unroll
      for (int r = 0; r < 4; r++) oacc[ni][r] *= al[r];

    // stage next tile into the other buffer (LDS writes drain before barrier)
    if (more) KV_WRITE(cur ^ 1);

    // O += P V  (P per-wave rows — no barrier needed, lgkmcnt covers it)
    #pragma unroll
    for (int ks = 0; ks < 2; ks++){
      int prow = w*16 + l15;
      int pcc = (ks*4 + quad) ^ (prow & 7);
      short8 pa = *(const short8*)&Ps[prow*64 + pcc*8];
      __builtin_amdgcn_s_setprio(1);
      #pragma unroll
      for (int ni = 0; ni < 8; ni++){
        int d = ni*16 + l15;
        int vcc = (ks*4 + quad) ^ (d & 7);
        short8 vb = *(const short8*)&Vts[cur][d*64 + vcc*8];
        oacc[ni] = mfma16(pa, vb, oacc[ni]);
      }
      __builtin_amdgcn_s_setprio(0);
    }
    __syncthreads();
    cur ^= 1;
  }
#undef KV_LOAD
#undef KV_WRITE

  // epilogue: divide by l, write fp32 out
  float inv[4];
  #pragma unroll
  for (int r = 0; r < 4; r++) inv[r] = 1.0f / Ln[r];
  #pragma unroll
  for (int ni = 0; ni < 8; ni++)
    #pragma unroll
    for (int r = 0; r < 4; r++){
      int m = b*512 + qt*128 + w*16 + quad*4 + r;
      out[(size_t)m*4096 + h*128 + ni*16 + l15] = oacc[ni][r] * inv[r];
    }
}

extern "C" void kernel_launch(void* const* d_in, const int* in_sizes, int n_in,
                              void* d_out, int out_size, void* d_ws, size_t ws_size,
                              hipStream_t stream){
  const float* x    = (const float*)d_in[0];
  const int*   spp  = (const int*)d_in[1];
  const float* fcos = (const float*)d_in[2];
  const float* fsin = (const float*)d_in[3];
  const float* wq   = (const float*)d_in[4];
  const float* bq   = (const float*)d_in[5];
  const float* wk   = (const float*)d_in[6];
  const float* bk   = (const float*)d_in[7];
  const float* wv   = (const float*)d_in[8];
  const float* bv   = (const float*)d_in[9];
  float* ck = (float*)d_in[10];
  float* cv = (float*)d_in[11];
  float* out = (float*)d_out;

  unsigned short* xb = (unsigned short*)d_ws;
  unsigned short* Qb = xb + (size_t)2048*4096;
  unsigned short* wb = Qb + (size_t)2048*4096;
  const size_t need_big = (size_t)2*2048*4096*2 + (size_t)3*4096*4096*2; // 128 MiB
  bool big = ws_size >= need_big;

  k_cvt<<<2048, 256, 0, stream>>>(x, xb, 2048*4096/4);
  if (big){
    k_cvt<<<4096, 256, 0, stream>>>(wq, wb,                       4096*4096/4);
    k_cvt<<<4096, 256, 0, stream>>>(wk, wb + (size_t)4096*4096,   4096*4096/4);
    k_cvt<<<4096, 256, 0, stream>>>(wv, wb + (size_t)2*4096*4096, 4096*4096/4);
    k_gemm<1><<<dim3(512,1,3), 256, 0, stream>>>(xb, wb, wq, wk, wv, bq, bk, bv,
                                                 fcos, fsin, spp, Qb, ck, cv);
  } else {
    k_gemm<0><<<dim3(512,1,3), 256, 0, stream>>>(xb, wb, wq, wk, wv, bq, bk, bv,
                                                 fcos, fsin, spp, Qb, ck, cv);
  }
  k_attn<<<512, 512, 0, stream>>>(Qb, ck, cv, spp, out);
}